// Round 10
// baseline (16.318 us; speedup 1.0000x reference)
//
#include <hip/hip_runtime.h>

#define FXc 160.0f
#define FYc 160.0f
#define THRESHc 0.001f
#define EPSc 1e-6f
#define QTH 1024         // 16 waves
#define CAP 1000         // max hits kept per quad (est. worst ~450)

// One block per 8x8 pixel quad; zero cross-block dependencies.
__global__ __launch_bounds__(QTH) void fused_kernel(
    const float* __restrict__ mean, const float* __restrict__ qvec,
    const float* __restrict__ svec, const float* __restrict__ color,
    const float* __restrict__ alpha, const float* __restrict__ c2w,
    const int* __restrict__ Wp, const int* __restrict__ Hp,
    float* __restrict__ out, int n) {
    __shared__ unsigned long long key[CAP];   // depth_bits||idx (unique)
    __shared__ int   ord[CAP];                // sorted order -> slot
    __shared__ float4 pp0[CAP], pp1[CAP];     // params stored at append time
    __shared__ float  ppa[CAP];
    __shared__ float4 partial[16][64];
    __shared__ int cntS;

    int tid = threadIdx.x;
    int lane = tid & 63;
    int w = tid >> 6;

    int W = *Wp, H = *Hp;
    int qpx = (W + 7) >> 3;
    int q = blockIdx.x;
    int qx = q % qpx, qy = q / qpx;
    float cxofx = (W * 0.5f) / FXc, cyofy = (H * 0.5f) / FYc;
    float wx0 = ((float)(qx*8)   + 0.5f) / FXc - cxofx;
    float wx1 = ((float)(qx*8+7) + 0.5f) / FXc - cxofx;
    float wy0 = ((float)(qy*8)   + 0.5f) / FYc - cyofy;
    float wy1 = ((float)(qy*8+7) + 0.5f) / FYc - cyofy;
    int col = qx * 8 + (lane & 7);
    int row = qy * 8 + (lane >> 3);
    float px = ((float)col + 0.5f) / FXc - cxofx;
    float py = ((float)row + 0.5f) / FYc - cyofy;

    if (tid == 0) cntS = 0;
    __syncthreads();

    float tx = c2w[3], ty = c2w[7], tz = c2w[11];
    float W00 = c2w[0], W01 = c2w[4], W02 = c2w[8];
    float W10 = c2w[1], W11 = c2w[5], W12 = c2w[9];
    float W20 = c2w[2], W21 = c2w[6], W22 = c2w[10];

    // ---- phase 1: full params + exact bbox test + wave-aggregated append ----
    for (int base = 0; base < n; base += QTH) {
        int i = base + tid;
        bool hit = false;
        float m2x = 0.f, m2y = 0.f, h00 = 0.f, h01 = 0.f, h11 = 0.f;
        float cr = 0.f, cg = 0.f, cb = 0.f, al = 0.f, pmz = 0.f;
        if (i < n) {
            al = alpha[i];
            if (al > THRESHc) {
                float mx = mean[3*i+0] - tx, my = mean[3*i+1] - ty, mz = mean[3*i+2] - tz;
                float pmx = W00*mx + W01*my + W02*mz;
                float pmy = W10*mx + W11*my + W12*mz;
                pmz = W20*mx + W21*my + W22*mz;
                float qw = qvec[4*i+0], qxx = qvec[4*i+1], qyy = qvec[4*i+2], qzz = qvec[4*i+3];
                float qinv = rsqrtf(qw*qw + qxx*qxx + qyy*qyy + qzz*qzz);
                qw *= qinv; qxx *= qinv; qyy *= qinv; qzz *= qinv;
                float R00 = 1.0f - 2.0f*(qyy*qyy + qzz*qzz), R01 = 2.0f*(qxx*qyy - qw*qzz), R02 = 2.0f*(qxx*qzz + qw*qyy);
                float R10 = 2.0f*(qxx*qyy + qw*qzz), R11 = 1.0f - 2.0f*(qxx*qxx + qzz*qzz), R12 = 2.0f*(qyy*qzz - qw*qxx);
                float R20 = 2.0f*(qxx*qzz - qw*qyy), R21 = 2.0f*(qyy*qzz + qw*qxx), R22 = 1.0f - 2.0f*(qxx*qxx + qyy*qyy);
                float sx = svec[3*i+0], sy = svec[3*i+1], sz = svec[3*i+2];
                float M00 = R00*sx, M01 = R01*sy, M02 = R02*sz;
                float M10 = R10*sx, M11 = R11*sy, M12 = R12*sz;
                float M20 = R20*sx, M21 = R21*sy, M22 = R22*sz;
                float iz = 1.0f / pmz, iz2 = iz*iz;
                float axx = pmx*iz2, ayy = pmy*iz2;
                float A0 = iz*W00 - axx*W20, A1 = iz*W01 - axx*W21, A2 = iz*W02 - axx*W22;
                float B0 = iz*W10 - ayy*W20, B1 = iz*W11 - ayy*W21, B2 = iz*W12 - ayy*W22;
                float V00 = A0*M00 + A1*M10 + A2*M20;
                float V01 = A0*M01 + A1*M11 + A2*M21;
                float V02 = A0*M02 + A1*M12 + A2*M22;
                float V10 = B0*M00 + B1*M10 + B2*M20;
                float V11 = B0*M01 + B1*M11 + B2*M21;
                float V12 = B0*M02 + B1*M12 + B2*M22;
                float a  = V00*V00 + V01*V01 + V02*V02 + EPSc;
                float bb = V00*V10 + V01*V11 + V02*V12;
                float dd = V10*V10 + V11*V11 + V12*V12 + EPSc;
                float det  = a*dd - bb*bb;
                float idet = 1.0f / det;
                h00 = -0.5f * dd * idet;
                h01 =  bb * idet;
                h11 = -0.5f * a  * idet;
                m2x = pmx*iz; m2y = pmy*iz;
                float cc = logf(al / THRESHc);
                float ex = sqrtf(2.0f*cc*a)  * 1.0009f + 1e-6f;
                float ey = sqrtf(2.0f*cc*dd) * 1.0009f + 1e-6f;
                hit = !(m2x + ex < wx0 || m2x - ex > wx1 ||
                        m2y + ey < wy0 || m2y - ey > wy1);
                if (hit) { cr = color[3*i+0]; cg = color[3*i+1]; cb = color[3*i+2]; }
            }
        }
        unsigned long long mb = __ballot(hit);
        if (mb) {
            int leader = __builtin_ctzll(mb);
            int cw = (int)__popcll(mb);
            int basep = 0;
            if (lane == leader) basep = atomicAdd(&cntS, cw);
            basep = __shfl(basep, leader);
            if (hit) {
                int slot = basep + (int)__popcll(mb & ((1ull << lane) - 1ull));
                if (slot < CAP) {
                    unsigned fb = __float_as_uint(pmz);
                    fb = (fb & 0x80000000u) ? ~fb : (fb | 0x80000000u);
                    key[slot] = ((unsigned long long)fb << 32) | (unsigned)i;
                    pp0[slot] = make_float4(m2x, m2y, h00, h01);
                    pp1[slot] = make_float4(h11, cr, cg, cb);
                    ppa[slot] = al;
                }
            }
        }
    }
    __syncthreads();
    int c = min(cntS, CAP);

    // ---- phase 2: position-count sort (lockstep broadcast reads) -----------
    for (int k = tid; k < c; k += QTH) {
        unsigned long long e = key[k];
        int pos = 0;
        for (int m = 0; m < c; ++m) pos += (key[m] < e);
        ord[pos] = k;                        // unique keys -> bijection
    }
    __syncthreads();

    // ---- phase 3: 16-way sliced blend + in-block depth-order fold ----------
    int sl = (c + 15) >> 4;
    int b0 = min(c, w * sl), b1 = min(c, b0 + sl);
    float T = 1.0f, r = 0.0f, g = 0.0f, b = 0.0f;
    for (int j = b0; j < b1; ++j) {
        int s = ord[j];                      // broadcast
        float4 a0 = pp0[s];                  // broadcast
        float4 a1 = pp1[s];
        float  al = ppa[s];
        float dx = px - a0.x;
        float dy = py - a0.y;
        float pw = dx * (a0.z * dx + a0.w * dy) + a1.x * dy * dy;
        float ww = al * __expf(pw);
        ww = fminf(ww, 0.999f);
        ww = (ww > THRESHc) ? ww : 0.0f;
        float wT = ww * T;
        r = fmaf(wT, a1.y, r);
        g = fmaf(wT, a1.z, g);
        b = fmaf(wT, a1.w, b);
        T = T - wT;
    }
    partial[w][lane] = make_float4(r, g, b, T);
    __syncthreads();

    if (w == 0) {
        float Tf = 1.0f, rf = 0.0f, gf = 0.0f, bf = 0.0f;
#pragma unroll
        for (int s = 0; s < 16; ++s) {
            float4 v = partial[s][lane];
            rf = fmaf(Tf, v.x, rf);
            gf = fmaf(Tf, v.y, gf);
            bf = fmaf(Tf, v.z, bf);
            Tf *= v.w;
        }
        if (col < W && row < H) {
            int p = row * W + col;
            out[3*p+0] = rf;
            out[3*p+1] = gf;
            out[3*p+2] = bf;
        }
    }
}

extern "C" void kernel_launch(void* const* d_in, const int* in_sizes, int n_in,
                              void* d_out, int out_size, void* d_ws, size_t ws_size,
                              hipStream_t stream) {
    const float* mean  = (const float*)d_in[0];
    const float* qvec  = (const float*)d_in[1];
    const float* svec  = (const float*)d_in[2];
    const float* color = (const float*)d_in[3];
    const float* alpha = (const float*)d_in[4];
    const float* c2w   = (const float*)d_in[5];
    const int*   Hp    = (const int*)d_in[6];
    const int*   Wp    = (const int*)d_in[7];
    float* out = (float*)d_out;

    int n = in_sizes[0] / 3;
    int npix = out_size / 3;
    int Wh = 128;                            // problem constant; device reads W,H
    int Hh = npix / Wh;
    int quads = ((Wh + 7) / 8) * ((Hh + 7) / 8);

    fused_kernel<<<quads, QTH, 0, stream>>>(mean, qvec, svec, color, alpha, c2w,
                                            Wp, Hp, out, n);
}

// Round 11
// 15.545 us; speedup vs baseline: 1.0497x; 1.0497x over previous
//
#include <hip/hip_runtime.h>

#define FXc 160.0f
#define FYc 160.0f
#define THRESHc 0.001f
#define EPSc 1e-6f
#define QTH 1024         // 16 waves
#define CAP 1024         // max hits kept per quad (exact-bbox worst ~400)

// One block per 8x8 pixel quad; zero cross-block dependencies.
__global__ __launch_bounds__(QTH) void fused_kernel(
    const float* __restrict__ mean, const float* __restrict__ qvec,
    const float* __restrict__ svec, const float* __restrict__ color,
    const float* __restrict__ alpha, const float* __restrict__ c2w,
    const int* __restrict__ Wp, const int* __restrict__ Hp,
    float* __restrict__ out, int n) {
    __shared__ unsigned long long key[CAP];   // depth_bits||idx (unique)
    __shared__ int   ord[CAP];
    __shared__ float4 pp0[CAP], pp1[CAP];
    __shared__ float  ppa[CAP];
    __shared__ float4 partial[16][64];
    __shared__ int cntS;

    int tid = threadIdx.x;
    int lane = tid & 63;
    int w = tid >> 6;

    int W = *Wp, H = *Hp;
    int qpx = (W + 7) >> 3;
    int q = blockIdx.x;
    int qx = q % qpx, qy = q / qpx;
    float cxofx = (W * 0.5f) / FXc, cyofy = (H * 0.5f) / FYc;
    float wx0 = ((float)(qx*8)   + 0.5f) / FXc - cxofx;
    float wx1 = ((float)(qx*8+7) + 0.5f) / FXc - cxofx;
    float wy0 = ((float)(qy*8)   + 0.5f) / FYc - cyofy;
    float wy1 = ((float)(qy*8+7) + 0.5f) / FYc - cyofy;
    int col = qx * 8 + (lane & 7);
    int row = qy * 8 + (lane >> 3);
    float px = ((float)col + 0.5f) / FXc - cxofx;
    float py = ((float)row + 0.5f) / FYc - cyofy;

    if (tid == 0) cntS = 0;
    __syncthreads();

    float tx = c2w[3], ty = c2w[7], tz = c2w[11];
    float W00 = c2w[0], W01 = c2w[4], W02 = c2w[8];
    float W10 = c2w[1], W11 = c2w[5], W12 = c2w[9];
    float W20 = c2w[2], W21 = c2w[6], W22 = c2w[10];

    // ---- phase 1: full params + exact bbox test + wave-aggregated append ----
    // Pair-wise load hoist: issue both iterations' loads, then compute.
    for (int base = 0; base < n; base += 2 * QTH) {
        float lmx[2], lmy[2], lmz[2], lsx[2], lsy[2], lsz[2], lal[2];
        float4 lq[2];
#pragma unroll
        for (int u = 0; u < 2; ++u) {
            int i = base + u * QTH + tid;
            int ic = (i < n) ? i : 0;
            lmx[u] = mean[3*ic+0]; lmy[u] = mean[3*ic+1]; lmz[u] = mean[3*ic+2];
            lq[u]  = ((const float4*)qvec)[ic];
            lsx[u] = svec[3*ic+0]; lsy[u] = svec[3*ic+1]; lsz[u] = svec[3*ic+2];
            lal[u] = (i < n) ? alpha[ic] : 0.0f;
        }
#pragma unroll
        for (int u = 0; u < 2; ++u) {
            int i = base + u * QTH + tid;
            bool hit = false;
            float m2x = 0.f, m2y = 0.f, h00 = 0.f, h01 = 0.f, h11 = 0.f;
            float al = lal[u], pmz = 0.f;
            if (i < n && al > THRESHc) {
                float mx = lmx[u] - tx, my = lmy[u] - ty, mz = lmz[u] - tz;
                float pmx = W00*mx + W01*my + W02*mz;
                float pmy = W10*mx + W11*my + W12*mz;
                pmz = W20*mx + W21*my + W22*mz;
                float qw = lq[u].x, qxx = lq[u].y, qyy = lq[u].z, qzz = lq[u].w;
                float qinv = rsqrtf(qw*qw + qxx*qxx + qyy*qyy + qzz*qzz);
                qw *= qinv; qxx *= qinv; qyy *= qinv; qzz *= qinv;
                float R00 = 1.0f - 2.0f*(qyy*qyy + qzz*qzz), R01 = 2.0f*(qxx*qyy - qw*qzz), R02 = 2.0f*(qxx*qzz + qw*qyy);
                float R10 = 2.0f*(qxx*qyy + qw*qzz), R11 = 1.0f - 2.0f*(qxx*qxx + qzz*qzz), R12 = 2.0f*(qyy*qzz - qw*qxx);
                float R20 = 2.0f*(qxx*qzz - qw*qyy), R21 = 2.0f*(qyy*qzz + qw*qxx), R22 = 1.0f - 2.0f*(qxx*qxx + qyy*qyy);
                float sx = lsx[u], sy = lsy[u], sz = lsz[u];
                float M00 = R00*sx, M01 = R01*sy, M02 = R02*sz;
                float M10 = R10*sx, M11 = R11*sy, M12 = R12*sz;
                float M20 = R20*sx, M21 = R21*sy, M22 = R22*sz;
                float iz = 1.0f / pmz, iz2 = iz*iz;
                float axx = pmx*iz2, ayy = pmy*iz2;
                float A0 = iz*W00 - axx*W20, A1 = iz*W01 - axx*W21, A2 = iz*W02 - axx*W22;
                float B0 = iz*W10 - ayy*W20, B1 = iz*W11 - ayy*W21, B2 = iz*W12 - ayy*W22;
                float V00 = A0*M00 + A1*M10 + A2*M20;
                float V01 = A0*M01 + A1*M11 + A2*M21;
                float V02 = A0*M02 + A1*M12 + A2*M22;
                float V10 = B0*M00 + B1*M10 + B2*M20;
                float V11 = B0*M01 + B1*M11 + B2*M21;
                float V12 = B0*M02 + B1*M12 + B2*M22;
                float a  = V00*V00 + V01*V01 + V02*V02 + EPSc;
                float bb = V00*V10 + V01*V11 + V02*V12;
                float dd = V10*V10 + V11*V11 + V12*V12 + EPSc;
                float det  = a*dd - bb*bb;
                float idet = 1.0f / det;
                h00 = -0.5f * dd * idet;
                h01 =  bb * idet;
                h11 = -0.5f * a  * idet;
                m2x = pmx*iz; m2y = pmy*iz;
                float cc = __logf(al * (1.0f / THRESHc));
                float ex = __builtin_sqrtf(2.0f*cc*a)  * 1.0009f + 1e-6f;
                float ey = __builtin_sqrtf(2.0f*cc*dd) * 1.0009f + 1e-6f;
                hit = !(m2x + ex < wx0 || m2x - ex > wx1 ||
                        m2y + ey < wy0 || m2y - ey > wy1);
            }
            unsigned long long mb = __ballot(hit);
            if (mb) {
                int leader = __builtin_ctzll(mb);
                int cw = (int)__popcll(mb);
                int basep = 0;
                if (lane == leader) basep = atomicAdd(&cntS, cw);
                basep = __shfl(basep, leader);
                if (hit) {
                    int slot = basep + (int)__popcll(mb & ((1ull << lane) - 1ull));
                    if (slot < CAP) {
                        unsigned fb = __float_as_uint(pmz);
                        fb = (fb & 0x80000000u) ? ~fb : (fb | 0x80000000u);
                        key[slot] = ((unsigned long long)fb << 32) | (unsigned)i;
                        pp0[slot] = make_float4(m2x, m2y, h00, h01);
                        pp1[slot] = make_float4(h11, color[3*i+0], color[3*i+1], color[3*i+2]);
                        ppa[slot] = al;
                    }
                }
            }
        }
    }
    __syncthreads();
    int c = min(cntS, CAP);

    // ---- phase 2: position-count sort (lockstep broadcast reads) -----------
    for (int k = tid; k < c; k += QTH) {
        unsigned long long e = key[k];
        int pos = 0;
        for (int m = 0; m < c; ++m) pos += (key[m] < e);
        ord[pos] = k;                        // unique keys -> bijection
    }
    __syncthreads();

    // ---- phase 3: 16-way sliced blend + in-block depth-order fold ----------
    int sl = (c + 15) >> 4;
    int b0 = min(c, w * sl), b1 = min(c, b0 + sl);
    float T = 1.0f, r = 0.0f, g = 0.0f, b = 0.0f;
    for (int j = b0; j < b1; ++j) {
        int s = ord[j];                      // broadcast
        float4 a0 = pp0[s];                  // broadcast
        float4 a1 = pp1[s];
        float  al = ppa[s];
        float dx = px - a0.x;
        float dy = py - a0.y;
        float pw = dx * (a0.z * dx + a0.w * dy) + a1.x * dy * dy;
        float ww = al * __expf(pw);
        ww = fminf(ww, 0.999f);
        ww = (ww > THRESHc) ? ww : 0.0f;
        float wT = ww * T;
        r = fmaf(wT, a1.y, r);
        g = fmaf(wT, a1.z, g);
        b = fmaf(wT, a1.w, b);
        T = T - wT;
    }
    partial[w][lane] = make_float4(r, g, b, T);
    __syncthreads();

    if (w == 0) {
        float Tf = 1.0f, rf = 0.0f, gf = 0.0f, bf = 0.0f;
#pragma unroll
        for (int s = 0; s < 16; ++s) {
            float4 v = partial[s][lane];
            rf = fmaf(Tf, v.x, rf);
            gf = fmaf(Tf, v.y, gf);
            bf = fmaf(Tf, v.z, bf);
            Tf *= v.w;
        }
        if (col < W && row < H) {
            int p = row * W + col;
            out[3*p+0] = rf;
            out[3*p+1] = gf;
            out[3*p+2] = bf;
        }
    }
}

extern "C" void kernel_launch(void* const* d_in, const int* in_sizes, int n_in,
                              void* d_out, int out_size, void* d_ws, size_t ws_size,
                              hipStream_t stream) {
    const float* mean  = (const float*)d_in[0];
    const float* qvec  = (const float*)d_in[1];
    const float* svec  = (const float*)d_in[2];
    const float* color = (const float*)d_in[3];
    const float* alpha = (const float*)d_in[4];
    const float* c2w   = (const float*)d_in[5];
    const int*   Hp    = (const int*)d_in[6];
    const int*   Wp    = (const int*)d_in[7];
    float* out = (float*)d_out;

    int n = in_sizes[0] / 3;
    int npix = out_size / 3;
    int Wh = 128;                            // problem constant; device reads W,H
    int Hh = npix / Wh;
    int quads = ((Wh + 7) / 8) * ((Hh + 7) / 8);

    fused_kernel<<<quads, QTH, 0, stream>>>(mean, qvec, svec, color, alpha, c2w,
                                            Wp, Hp, out, n);
}

// Round 12
// 14.810 us; speedup vs baseline: 1.1018x; 1.0497x over previous
//
#include <hip/hip_runtime.h>

#define FXc 160.0f
#define FYc 160.0f
#define THRESHc 0.001f
#define EPSc 1e-6f
#define QTH 1024         // 16 waves
#define CAP 1024         // max exact hits kept per quad
#define CCAP 2048        // max candidates per quad (= n)

// One block per 8x8 pixel quad; zero cross-block dependencies.
__global__ __launch_bounds__(QTH) void fused_kernel(
    const float* __restrict__ mean, const float* __restrict__ qvec,
    const float* __restrict__ svec, const float* __restrict__ color,
    const float* __restrict__ alpha, const float* __restrict__ c2w,
    const int* __restrict__ Wp, const int* __restrict__ Hp,
    float* __restrict__ out, int n) {
    __shared__ unsigned long long key[CAP];   // depth_bits||idx (unique)
    __shared__ int   ord[CAP];
    __shared__ float4 pp0[CAP], pp1[CAP];
    __shared__ float  ppa[CAP];
    __shared__ float4 partial[16][64];
    __shared__ int   cand[CCAP];
    __shared__ int cntS, candS;

    int tid = threadIdx.x;
    int lane = tid & 63;
    int w = tid >> 6;

    int W = *Wp, H = *Hp;
    int qpx = (W + 7) >> 3;
    int q = blockIdx.x;
    int qx = q % qpx, qy = q / qpx;
    float cxofx = (W * 0.5f) / FXc, cyofy = (H * 0.5f) / FYc;
    float wx0 = ((float)(qx*8)   + 0.5f) / FXc - cxofx;
    float wx1 = ((float)(qx*8+7) + 0.5f) / FXc - cxofx;
    float wy0 = ((float)(qy*8)   + 0.5f) / FYc - cyofy;
    float wy1 = ((float)(qy*8+7) + 0.5f) / FYc - cyofy;
    int col = qx * 8 + (lane & 7);
    int row = qy * 8 + (lane >> 3);
    float px = ((float)col + 0.5f) / FXc - cxofx;
    float py = ((float)row + 0.5f) / FYc - cyofy;

    if (tid == 0) { cntS = 0; candS = 0; }
    __syncthreads();

    float tx = c2w[3], ty = c2w[7], tz = c2w[11];
    float W00 = c2w[0], W01 = c2w[4], W02 = c2w[8];
    float W10 = c2w[1], W11 = c2w[5], W12 = c2w[9];
    float W20 = c2w[2], W21 = c2w[6], W22 = c2w[10];

    // ---- phase 1a: cheap conservative prefilter (no quaternion math) -------
    // R columns orthonormal => |V_row|^2 <= smax^2 * |A|^2, |A|^2 = iz^2+ax^2.
    for (int base = 0; base < n; base += QTH) {
        int i = base + tid;
        bool cd = false;
        if (i < n) {
            float al = alpha[i];
            if (al > THRESHc) {
                float mx = mean[3*i+0] - tx, my = mean[3*i+1] - ty, mz = mean[3*i+2] - tz;
                float pmx = W00*mx + W01*my + W02*mz;
                float pmy = W10*mx + W11*my + W12*mz;
                float pmz = W20*mx + W21*my + W22*mz;
                float sx = svec[3*i+0], sy = svec[3*i+1], sz = svec[3*i+2];
                float smax = fmaxf(sx, fmaxf(sy, sz));
                float s2 = smax * smax;
                float iz = 1.0f / pmz, iz2 = iz*iz;
                float ax = pmx*iz2, ay = pmy*iz2;
                float ab = s2*(iz2 + ax*ax) + EPSc;
                float db = s2*(iz2 + ay*ay) + EPSc;
                float cc = __logf(al * (1.0f / THRESHc));
                float exb = __builtin_sqrtf(2.0f*cc*ab) * 1.003f + 2e-6f;
                float eyb = __builtin_sqrtf(2.0f*cc*db) * 1.003f + 2e-6f;
                float m2x = pmx*iz, m2y = pmy*iz;
                cd = !(m2x + exb < wx0 || m2x - exb > wx1 ||
                       m2y + eyb < wy0 || m2y - eyb > wy1);
            }
        }
        unsigned long long mb = __ballot(cd);
        if (mb) {
            int leader = __builtin_ctzll(mb);
            int cw = (int)__popcll(mb);
            int basep = 0;
            if (lane == leader) basep = atomicAdd(&candS, cw);
            basep = __shfl(basep, leader);
            if (cd) {
                int slot = basep + (int)__popcll(mb & ((1ull << lane) - 1ull));
                if (slot < CCAP) cand[slot] = i;
            }
        }
    }
    __syncthreads();
    int nc = min(candS, CCAP);

    // ---- phase 1b: full params + exact bbox test on compacted candidates ----
    for (int base = 0; base < nc; base += QTH) {
        int k = base + tid;
        bool hit = false;
        float m2x = 0.f, m2y = 0.f, h00 = 0.f, h01 = 0.f, h11 = 0.f;
        float al = 0.f, pmz = 0.f;
        int i = 0;
        if (k < nc) {
            i = cand[k];
            al = alpha[i];
            float mx = mean[3*i+0] - tx, my = mean[3*i+1] - ty, mz = mean[3*i+2] - tz;
            float pmx = W00*mx + W01*my + W02*mz;
            float pmy = W10*mx + W11*my + W12*mz;
            pmz = W20*mx + W21*my + W22*mz;
            float4 qv = ((const float4*)qvec)[i];
            float qw = qv.x, qxx = qv.y, qyy = qv.z, qzz = qv.w;
            float qinv = rsqrtf(qw*qw + qxx*qxx + qyy*qyy + qzz*qzz);
            qw *= qinv; qxx *= qinv; qyy *= qinv; qzz *= qinv;
            float R00 = 1.0f - 2.0f*(qyy*qyy + qzz*qzz), R01 = 2.0f*(qxx*qyy - qw*qzz), R02 = 2.0f*(qxx*qzz + qw*qyy);
            float R10 = 2.0f*(qxx*qyy + qw*qzz), R11 = 1.0f - 2.0f*(qxx*qxx + qzz*qzz), R12 = 2.0f*(qyy*qzz - qw*qxx);
            float R20 = 2.0f*(qxx*qzz - qw*qyy), R21 = 2.0f*(qyy*qzz + qw*qxx), R22 = 1.0f - 2.0f*(qxx*qxx + qyy*qyy);
            float sx = svec[3*i+0], sy = svec[3*i+1], sz = svec[3*i+2];
            float M00 = R00*sx, M01 = R01*sy, M02 = R02*sz;
            float M10 = R10*sx, M11 = R11*sy, M12 = R12*sz;
            float M20 = R20*sx, M21 = R21*sy, M22 = R22*sz;
            float iz = 1.0f / pmz, iz2 = iz*iz;
            float axx = pmx*iz2, ayy = pmy*iz2;
            float A0 = iz*W00 - axx*W20, A1 = iz*W01 - axx*W21, A2 = iz*W02 - axx*W22;
            float B0 = iz*W10 - ayy*W20, B1 = iz*W11 - ayy*W21, B2 = iz*W12 - ayy*W22;
            float V00 = A0*M00 + A1*M10 + A2*M20;
            float V01 = A0*M01 + A1*M11 + A2*M21;
            float V02 = A0*M02 + A1*M12 + A2*M22;
            float V10 = B0*M00 + B1*M10 + B2*M20;
            float V11 = B0*M01 + B1*M11 + B2*M21;
            float V12 = B0*M02 + B1*M12 + B2*M22;
            float a  = V00*V00 + V01*V01 + V02*V02 + EPSc;
            float bb = V00*V10 + V01*V11 + V02*V12;
            float dd = V10*V10 + V11*V11 + V12*V12 + EPSc;
            float det  = a*dd - bb*bb;
            float idet = 1.0f / det;
            h00 = -0.5f * dd * idet;
            h01 =  bb * idet;
            h11 = -0.5f * a  * idet;
            m2x = pmx*iz; m2y = pmy*iz;
            float cc = __logf(al * (1.0f / THRESHc));
            float ex = __builtin_sqrtf(2.0f*cc*a)  * 1.0009f + 1e-6f;
            float ey = __builtin_sqrtf(2.0f*cc*dd) * 1.0009f + 1e-6f;
            hit = !(m2x + ex < wx0 || m2x - ex > wx1 ||
                    m2y + ey < wy0 || m2y - ey > wy1);
        }
        unsigned long long mb = __ballot(hit);
        if (mb) {
            int leader = __builtin_ctzll(mb);
            int cw = (int)__popcll(mb);
            int basep = 0;
            if (lane == leader) basep = atomicAdd(&cntS, cw);
            basep = __shfl(basep, leader);
            if (hit) {
                int slot = basep + (int)__popcll(mb & ((1ull << lane) - 1ull));
                if (slot < CAP) {
                    unsigned fb = __float_as_uint(pmz);
                    fb = (fb & 0x80000000u) ? ~fb : (fb | 0x80000000u);
                    key[slot] = ((unsigned long long)fb << 32) | (unsigned)i;
                    pp0[slot] = make_float4(m2x, m2y, h00, h01);
                    pp1[slot] = make_float4(h11, color[3*i+0], color[3*i+1], color[3*i+2]);
                    ppa[slot] = al;
                }
            }
        }
    }
    __syncthreads();
    int c = min(cntS, CAP);

    // ---- phase 2: position-count sort (lockstep broadcast reads) -----------
    for (int k = tid; k < c; k += QTH) {
        unsigned long long e = key[k];
        int pos = 0;
        for (int m = 0; m < c; ++m) pos += (key[m] < e);
        ord[pos] = k;                        // unique keys -> bijection
    }
    __syncthreads();

    // ---- phase 3: 16-way sliced blend + in-block depth-order fold ----------
    int sl = (c + 15) >> 4;
    int b0 = min(c, w * sl), b1 = min(c, b0 + sl);
    float T = 1.0f, r = 0.0f, g = 0.0f, b = 0.0f;
    for (int j = b0; j < b1; ++j) {
        int s = ord[j];                      // broadcast
        float4 a0 = pp0[s];                  // broadcast
        float4 a1 = pp1[s];
        float  al = ppa[s];
        float dx = px - a0.x;
        float dy = py - a0.y;
        float pw = dx * (a0.z * dx + a0.w * dy) + a1.x * dy * dy;
        float ww = al * __expf(pw);
        ww = fminf(ww, 0.999f);
        ww = (ww > THRESHc) ? ww : 0.0f;
        float wT = ww * T;
        r = fmaf(wT, a1.y, r);
        g = fmaf(wT, a1.z, g);
        b = fmaf(wT, a1.w, b);
        T = T - wT;
    }
    partial[w][lane] = make_float4(r, g, b, T);
    __syncthreads();

    if (w == 0) {
        float Tf = 1.0f, rf = 0.0f, gf = 0.0f, bf = 0.0f;
#pragma unroll
        for (int s = 0; s < 16; ++s) {
            float4 v = partial[s][lane];
            rf = fmaf(Tf, v.x, rf);
            gf = fmaf(Tf, v.y, gf);
            bf = fmaf(Tf, v.z, bf);
            Tf *= v.w;
        }
        if (col < W && row < H) {
            int p = row * W + col;
            out[3*p+0] = rf;
            out[3*p+1] = gf;
            out[3*p+2] = bf;
        }
    }
}

extern "C" void kernel_launch(void* const* d_in, const int* in_sizes, int n_in,
                              void* d_out, int out_size, void* d_ws, size_t ws_size,
                              hipStream_t stream) {
    const float* mean  = (const float*)d_in[0];
    const float* qvec  = (const float*)d_in[1];
    const float* svec  = (const float*)d_in[2];
    const float* color = (const float*)d_in[3];
    const float* alpha = (const float*)d_in[4];
    const float* c2w   = (const float*)d_in[5];
    const int*   Hp    = (const int*)d_in[6];
    const int*   Wp    = (const int*)d_in[7];
    float* out = (float*)d_out;

    int n = in_sizes[0] / 3;
    int npix = out_size / 3;
    int Wh = 128;                            // problem constant; device reads W,H
    int Hh = npix / Wh;
    int quads = ((Wh + 7) / 8) * ((Hh + 7) / 8);

    fused_kernel<<<quads, QTH, 0, stream>>>(mean, qvec, svec, color, alpha, c2w,
                                            Wp, Hp, out, n);
}

// Round 13
// 14.788 us; speedup vs baseline: 1.1035x; 1.0015x over previous
//
#include <hip/hip_runtime.h>

#define FXc 160.0f
#define FYc 160.0f
#define THRESHc 0.001f
#define EPSc 1e-6f
#define QTH 1024         // 16 waves
#define CAP 1024         // max exact hits kept per quad
#define CCAP 2048        // max candidates per quad (= n)

// One block per 8x8 pixel quad; zero cross-block dependencies.
__global__ __launch_bounds__(QTH) void fused_kernel(
    const float* __restrict__ mean, const float* __restrict__ qvec,
    const float* __restrict__ svec, const float* __restrict__ color,
    const float* __restrict__ alpha, const float* __restrict__ c2w,
    const int* __restrict__ Wp, const int* __restrict__ Hp,
    float* __restrict__ out, int n) {
    __shared__ unsigned long long key[CAP];   // depth_bits||idx (unique)
    __shared__ float4 pp0[CAP], pp1[CAP];     // params at append slot
    __shared__ float  ppa[CAP];
    __shared__ float4 pps0[CAP], pps1[CAP];   // depth-sorted copies
    __shared__ float  ppsa[CAP];
    __shared__ float4 partial[16][64];
    __shared__ int   cand[CCAP];
    __shared__ int cntS, candS;

    int tid = threadIdx.x;
    int lane = tid & 63;
    int w = tid >> 6;

    int W = *Wp, H = *Hp;
    int qpx = (W + 7) >> 3;
    int q = blockIdx.x;
    int qx = q % qpx, qy = q / qpx;
    float cxofx = (W * 0.5f) / FXc, cyofy = (H * 0.5f) / FYc;
    float wx0 = ((float)(qx*8)   + 0.5f) / FXc - cxofx;
    float wx1 = ((float)(qx*8+7) + 0.5f) / FXc - cxofx;
    float wy0 = ((float)(qy*8)   + 0.5f) / FYc - cyofy;
    float wy1 = ((float)(qy*8+7) + 0.5f) / FYc - cyofy;
    int col = qx * 8 + (lane & 7);
    int row = qy * 8 + (lane >> 3);
    float px = ((float)col + 0.5f) / FXc - cxofx;
    float py = ((float)row + 0.5f) / FYc - cyofy;

    if (tid == 0) { cntS = 0; candS = 0; }
    __syncthreads();

    float tx = c2w[3], ty = c2w[7], tz = c2w[11];
    float W00 = c2w[0], W01 = c2w[4], W02 = c2w[8];
    float W10 = c2w[1], W11 = c2w[5], W12 = c2w[9];
    float W20 = c2w[2], W21 = c2w[6], W22 = c2w[10];

    // ---- phase 1a: cheap conservative prefilter (no quaternion math) -------
    // R columns orthonormal => |V_row|^2 <= smax^2 * |A|^2, |A|^2 = iz^2+ax^2.
    for (int base = 0; base < n; base += QTH) {
        int i = base + tid;
        bool cd = false;
        if (i < n) {
            float al = alpha[i];
            if (al > THRESHc) {
                float mx = mean[3*i+0] - tx, my = mean[3*i+1] - ty, mz = mean[3*i+2] - tz;
                float pmx = W00*mx + W01*my + W02*mz;
                float pmy = W10*mx + W11*my + W12*mz;
                float pmz = W20*mx + W21*my + W22*mz;
                float sx = svec[3*i+0], sy = svec[3*i+1], sz = svec[3*i+2];
                float smax = fmaxf(sx, fmaxf(sy, sz));
                float s2 = smax * smax;
                float iz = 1.0f / pmz, iz2 = iz*iz;
                float ax = pmx*iz2, ay = pmy*iz2;
                float ab = s2*(iz2 + ax*ax) + EPSc;
                float db = s2*(iz2 + ay*ay) + EPSc;
                float cc = __logf(al * (1.0f / THRESHc));
                float exb = __builtin_sqrtf(2.0f*cc*ab) * 1.003f + 2e-6f;
                float eyb = __builtin_sqrtf(2.0f*cc*db) * 1.003f + 2e-6f;
                float m2x = pmx*iz, m2y = pmy*iz;
                cd = !(m2x + exb < wx0 || m2x - exb > wx1 ||
                       m2y + eyb < wy0 || m2y - eyb > wy1);
            }
        }
        unsigned long long mb = __ballot(cd);
        if (mb) {
            int leader = __builtin_ctzll(mb);
            int cw = (int)__popcll(mb);
            int basep = 0;
            if (lane == leader) basep = atomicAdd(&candS, cw);
            basep = __shfl(basep, leader);
            if (cd) {
                int slot = basep + (int)__popcll(mb & ((1ull << lane) - 1ull));
                if (slot < CCAP) cand[slot] = i;
            }
        }
    }
    __syncthreads();
    int nc = min(candS, CCAP);

    // ---- phase 1b: full params + exact bbox test on compacted candidates ----
    for (int base = 0; base < nc; base += QTH) {
        int k = base + tid;
        bool hit = false;
        float m2x = 0.f, m2y = 0.f, h00 = 0.f, h01 = 0.f, h11 = 0.f;
        float al = 0.f, pmz = 0.f;
        int i = 0;
        if (k < nc) {
            i = cand[k];
            al = alpha[i];
            float mx = mean[3*i+0] - tx, my = mean[3*i+1] - ty, mz = mean[3*i+2] - tz;
            float pmx = W00*mx + W01*my + W02*mz;
            float pmy = W10*mx + W11*my + W12*mz;
            pmz = W20*mx + W21*my + W22*mz;
            float4 qv = ((const float4*)qvec)[i];
            float qw = qv.x, qxx = qv.y, qyy = qv.z, qzz = qv.w;
            float qinv = rsqrtf(qw*qw + qxx*qxx + qyy*qyy + qzz*qzz);
            qw *= qinv; qxx *= qinv; qyy *= qinv; qzz *= qinv;
            float R00 = 1.0f - 2.0f*(qyy*qyy + qzz*qzz), R01 = 2.0f*(qxx*qyy - qw*qzz), R02 = 2.0f*(qxx*qzz + qw*qyy);
            float R10 = 2.0f*(qxx*qyy + qw*qzz), R11 = 1.0f - 2.0f*(qxx*qxx + qzz*qzz), R12 = 2.0f*(qyy*qzz - qw*qxx);
            float R20 = 2.0f*(qxx*qzz - qw*qyy), R21 = 2.0f*(qyy*qzz + qw*qxx), R22 = 1.0f - 2.0f*(qxx*qxx + qyy*qyy);
            float sx = svec[3*i+0], sy = svec[3*i+1], sz = svec[3*i+2];
            float M00 = R00*sx, M01 = R01*sy, M02 = R02*sz;
            float M10 = R10*sx, M11 = R11*sy, M12 = R12*sz;
            float M20 = R20*sx, M21 = R21*sy, M22 = R22*sz;
            float iz = 1.0f / pmz, iz2 = iz*iz;
            float axx = pmx*iz2, ayy = pmy*iz2;
            float A0 = iz*W00 - axx*W20, A1 = iz*W01 - axx*W21, A2 = iz*W02 - axx*W22;
            float B0 = iz*W10 - ayy*W20, B1 = iz*W11 - ayy*W21, B2 = iz*W12 - ayy*W22;
            float V00 = A0*M00 + A1*M10 + A2*M20;
            float V01 = A0*M01 + A1*M11 + A2*M21;
            float V02 = A0*M02 + A1*M12 + A2*M22;
            float V10 = B0*M00 + B1*M10 + B2*M20;
            float V11 = B0*M01 + B1*M11 + B2*M21;
            float V12 = B0*M02 + B1*M12 + B2*M22;
            float a  = V00*V00 + V01*V01 + V02*V02 + EPSc;
            float bb = V00*V10 + V01*V11 + V02*V12;
            float dd = V10*V10 + V11*V11 + V12*V12 + EPSc;
            float det  = a*dd - bb*bb;
            float idet = 1.0f / det;
            h00 = -0.5f * dd * idet;
            h01 =  bb * idet;
            h11 = -0.5f * a  * idet;
            m2x = pmx*iz; m2y = pmy*iz;
            float cc = __logf(al * (1.0f / THRESHc));
            float ex = __builtin_sqrtf(2.0f*cc*a)  * 1.0009f + 1e-6f;
            float ey = __builtin_sqrtf(2.0f*cc*dd) * 1.0009f + 1e-6f;
            hit = !(m2x + ex < wx0 || m2x - ex > wx1 ||
                    m2y + ey < wy0 || m2y - ey > wy1);
        }
        unsigned long long mb = __ballot(hit);
        if (mb) {
            int leader = __builtin_ctzll(mb);
            int cw = (int)__popcll(mb);
            int basep = 0;
            if (lane == leader) basep = atomicAdd(&cntS, cw);
            basep = __shfl(basep, leader);
            if (hit) {
                int slot = basep + (int)__popcll(mb & ((1ull << lane) - 1ull));
                if (slot < CAP) {
                    unsigned fb = __float_as_uint(pmz);
                    fb = (fb & 0x80000000u) ? ~fb : (fb | 0x80000000u);
                    key[slot] = ((unsigned long long)fb << 32) | (unsigned)i;
                    pp0[slot] = make_float4(m2x, m2y, h00, h01);
                    pp1[slot] = make_float4(h11, color[3*i+0], color[3*i+1], color[3*i+2]);
                    ppa[slot] = al;
                }
            }
        }
    }
    __syncthreads();
    int c = min(cntS, CAP);

    // ---- phase 2: 4-way split rank sort + direct scatter to sorted arrays --
    if (c <= 256) {
        int k = tid >> 2;                    // 4 threads per key
        int seg = tid & 3;
        if (k < c) {
            unsigned long long e = key[k];
            int cq = (c + 3) >> 2;
            int m0 = seg * cq, m1 = min(c, m0 + cq);
            int pos = 0;
            for (int m = m0; m < m1; ++m) pos += (key[m] < e);
            pos += __shfl_xor(pos, 1);       // groups of 4 never cross a wave
            pos += __shfl_xor(pos, 2);
            if (seg == 0) {                  // unique keys -> bijection
                pps0[pos] = pp0[k];
                pps1[pos] = pp1[k];
                ppsa[pos] = ppa[k];
            }
        }
    } else {                                 // rare fallback, c in (256,1024]
        for (int k = tid; k < c; k += QTH) {
            unsigned long long e = key[k];
            int pos = 0;
            for (int m = 0; m < c; ++m) pos += (key[m] < e);
            pps0[pos] = pp0[k];
            pps1[pos] = pp1[k];
            ppsa[pos] = ppa[k];
        }
    }
    __syncthreads();

    // ---- phase 3: 16-way sliced blend (linear LDS reads) + in-block fold ---
    int sl = (c + 15) >> 4;
    int b0 = min(c, w * sl), b1 = min(c, b0 + sl);
    float T = 1.0f, r = 0.0f, g = 0.0f, b = 0.0f;
    for (int j = b0; j < b1; ++j) {
        float4 a0 = pps0[j];                 // broadcast, induction address
        float4 a1 = pps1[j];
        float  al = ppsa[j];
        float dx = px - a0.x;
        float dy = py - a0.y;
        float pw = dx * (a0.z * dx + a0.w * dy) + a1.x * dy * dy;
        float ww = al * __expf(pw);
        ww = fminf(ww, 0.999f);
        ww = (ww > THRESHc) ? ww : 0.0f;
        float wT = ww * T;
        r = fmaf(wT, a1.y, r);
        g = fmaf(wT, a1.z, g);
        b = fmaf(wT, a1.w, b);
        T = T - wT;
    }
    partial[w][lane] = make_float4(r, g, b, T);
    __syncthreads();

    if (w == 0) {
        float Tf = 1.0f, rf = 0.0f, gf = 0.0f, bf = 0.0f;
#pragma unroll
        for (int s = 0; s < 16; ++s) {
            float4 v = partial[s][lane];
            rf = fmaf(Tf, v.x, rf);
            gf = fmaf(Tf, v.y, gf);
            bf = fmaf(Tf, v.z, bf);
            Tf *= v.w;
        }
        if (col < W && row < H) {
            int p = row * W + col;
            out[3*p+0] = rf;
            out[3*p+1] = gf;
            out[3*p+2] = bf;
        }
    }
}

extern "C" void kernel_launch(void* const* d_in, const int* in_sizes, int n_in,
                              void* d_out, int out_size, void* d_ws, size_t ws_size,
                              hipStream_t stream) {
    const float* mean  = (const float*)d_in[0];
    const float* qvec  = (const float*)d_in[1];
    const float* svec  = (const float*)d_in[2];
    const float* color = (const float*)d_in[3];
    const float* alpha = (const float*)d_in[4];
    const float* c2w   = (const float*)d_in[5];
    const int*   Hp    = (const int*)d_in[6];
    const int*   Wp    = (const int*)d_in[7];
    float* out = (float*)d_out;

    int n = in_sizes[0] / 3;
    int npix = out_size / 3;
    int Wh = 128;                            // problem constant; device reads W,H
    int Hh = npix / Wh;
    int quads = ((Wh + 7) / 8) * ((Hh + 7) / 8);

    fused_kernel<<<quads, QTH, 0, stream>>>(mean, qvec, svec, color, alpha, c2w,
                                            Wp, Hp, out, n);
}